// Round 3
// baseline (305.145 us; speedup 1.0000x reference)
//
#include <hip/hip_runtime.h>

#define B_DIM 8
#define N_DIM 2048
#define C_DIM 256
#define K_SEL 1024

typedef __attribute__((ext_vector_type(8))) short short8;
typedef __attribute__((ext_vector_type(4))) float f32x4;

__device__ __forceinline__ unsigned int bf16rne(float x) {
  unsigned int u = __float_as_uint(x);
  return (u + 0x7fffu + ((u >> 16) & 1u)) >> 16;
}

// ---------------- LayerNorm, numpy-bit-exact, LDS-staged (unchanged, verified) ----------------
__global__ __launch_bounds__(64) void ln_lds(const float* __restrict__ feat,
    const float* __restrict__ gamma, const float* __restrict__ beta,
    float* __restrict__ fbuf) {
  __shared__ float tile[256 * 64];   // 64 KB exactly
  const int t = threadIdx.x;
  const int m0 = blockIdx.x << 6;
  const int b = m0 >> 11, n0 = m0 & 2047;

  const int cg = t >> 4, nl4 = (t & 15) << 2;
  for (int pass = 0; pass < 64; ++pass) {
    const int c = (pass << 2) + cg;
    const float4 v = *(const float4*)(feat + (((long)((b << 8) + c)) << 11) + n0 + nl4);
    const int sw = c & 31;
    float* row = tile + (c << 6);
    row[(nl4 + 0) ^ sw] = v.x; row[(nl4 + 1) ^ sw] = v.y;
    row[(nl4 + 2) ^ sw] = v.z; row[(nl4 + 3) ^ sw] = v.w;
  }
  __syncthreads();

  // mean: sequential ascending single chain (numpy strided-axis outer reduction)
  float acc = tile[t];
  for (int c = 1; c < 256; ++c) acc = __fadd_rn(acc, tile[(c << 6) + (t ^ (c & 31))]);
  const float mu = __fdiv_rn(acc, 256.0f);

  // var: numpy pairwise (2 halves x 8 accumulators) on contiguous (x-mu)^2
  float pw[2];
#pragma unroll
  for (int blk = 0; blk < 2; ++blk) {
    const int c0 = blk << 7;
    float r8[8];
#pragma unroll
    for (int j = 0; j < 8; ++j) {
      float d = __fsub_rn(tile[((c0 + j) << 6) + (t ^ ((c0 + j) & 31))], mu);
      r8[j] = __fmul_rn(d, d);
    }
    for (int i = 8; i < 128; i += 8) {
#pragma unroll
      for (int j = 0; j < 8; ++j) {
        const int c = c0 + i + j;
        float d = __fsub_rn(tile[(c << 6) + (t ^ (c & 31))], mu);
        r8[j] = __fadd_rn(r8[j], __fmul_rn(d, d));
      }
    }
    pw[blk] = __fadd_rn(__fadd_rn(__fadd_rn(r8[0], r8[1]), __fadd_rn(r8[2], r8[3])),
                        __fadd_rn(__fadd_rn(r8[4], r8[5]), __fadd_rn(r8[6], r8[7])));
  }
  const float var = __fdiv_rn(__fadd_rn(pw[0], pw[1]), 256.0f);
  const float rs = __fdiv_rn(1.0f, __fsqrt_rn(__fadd_rn(var, 1e-6f)));

  float ga[4], be[4];
#pragma unroll
  for (int q = 0; q < 4; ++q) { ga[q] = gamma[(q << 6) + t]; be[q] = beta[(q << 6) + t]; }
  for (int r = 0; r < 64; ++r) {
    const float mu_r = __shfl(mu, r, 64);
    const float rs_r = __shfl(rs, r, 64);
    float* orow = fbuf + (((long)(m0 + r)) << 8);
#pragma unroll
    for (int q = 0; q < 4; ++q) {
      const int c = (q << 6) + t;
      const float x = tile[(c << 6) + (r ^ (c & 31))];
      orow[c] = __fadd_rn(__fmul_rn(__fmul_rn(__fsub_rn(x, mu_r), rs_r), ga[q]), be[q]);
    }
  }
}

// ---------------- fused down-GEMM + w-chain, 512 threads (bit-exact chains) ----------------
// v4: same plan as v3 (A broadcast from global, 2-group-deep static pipeline, 1 spanning
// B ds_read_b128 per kk) but the A pointer gets an OPAQUE per-lane zero
// (asm "+v") so the compiler CANNOT scalarize the loads. v3 failed because uniform
// addresses became s_load (VGPR=60, SGPR file too small for the pipeline, out-of-order
// scalar loads force lgkmcnt(0) drains -> latency-bound 82us @ 31% VALU). With vector
// global_load_dwordx4 the ab[4][8] file lives in VGPRs (~190, capped 256 by
// __launch_bounds__(512,2)) and waits are counted vmcnt(N) -> pipeline survives.
// FMA chain per (m,c) stays ascending-k single chain -> bit-exact w (top-k safe).
__global__ void __launch_bounds__(512, 2) wgemm_w(
    const float* __restrict__ A, const float* __restrict__ Wd1,
    const float* __restrict__ bd1, const float* __restrict__ Wd2,
    const float* __restrict__ bd2, float* __restrict__ wkey) {
  __shared__ __align__(16) char smem[65536];
  float* Bs0f = (float*)smem;                  // 16x260 f32 = 16640 B
  float* Bs1f = (float*)(smem + 16640);        // 16640 B (double buffer)
  float* H = (float*)smem;                     // 256x64 f32 = 64 KB (epilogue alias)

  const int t = threadIdx.x;
  const int m0 = blockIdx.x << 6;
  const int rowT = t >> 6, colT = t & 63;      // rowT uniform per wave
  const int bk = t >> 5, bl4 = (t & 31) << 2;  // staging: lane-consecutive float4s

  // opaque zero: defeats uniform-address scalar-load conversion (value is 0 in every lane,
  // so all lanes load the same address -> single broadcast transaction, but via vector pipe)
  int zero0 = 0;
  asm volatile("" : "+v"(zero0));
  const float* aw = A + ((long)(m0 + (rowT << 3)) << 8) + zero0;  // wave's 8 rows

  float acc[8][4] = {};

  // B prologue: stage chunk 0 into Bs0 (conflict-free: lanes write consecutive float4s)
  {
    const float* brow = Wd1 + (bk << 8);
    *(float4*)(Bs0f + bk * 260 + bl4)       = *(const float4*)(brow + bl4);
    *(float4*)(Bs0f + bk * 260 + bl4 + 128) = *(const float4*)(brow + bl4 + 128);
  }

  // A pipeline prologue: groups 0,1 (k=0..3, 4..7) into buffers 0,1
  float4 ab[4][8];
#pragma unroll
  for (int i = 0; i < 8; ++i) ab[0][i] = *(const float4*)(aw + (i << 8) + 0);
#pragma unroll
  for (int i = 0; i < 8; ++i) ab[1][i] = *(const float4*)(aw + (i << 8) + 4);

  __syncthreads();

  const float* Bc = Bs0f;
  float* Bn = Bs1f;
  for (int c16 = 0; c16 < 16; ++c16) {
    // issue next B-chunk global loads (wraps on last iter; then unused)
    float4 r0, r1;
    {
      const int knext = (c16 + 1) & 15;
      const float* brow = Wd1 + (((knext << 4) + bk) << 8);
      r0 = *(const float4*)(brow + bl4);
      r1 = *(const float4*)(brow + bl4 + 128);
    }
#pragma unroll
    for (int g = 0; g < 4; ++g) {               // group G = c16*4+g covers k=4G..4G+3
      // prefetch A for group G+2 into buffer (g+2)&3 (~2 groups / ~1000 cyc ahead)
      const int kpre = (((c16 << 2) + g + 2) << 2) & 255;
#pragma unroll
      for (int i = 0; i < 8; ++i)
        ab[(g + 2) & 3][i] = *(const float4*)(aw + (i << 8) + kpre);
#pragma unroll
      for (int kk = 0; kk < 4; ++kk) {          // k ascending: single FMA chain per (m,c)
        const float4 b = *(const float4*)(Bc + ((g << 2) + kk) * 260 + (colT << 2));
        const float bbv[4] = {b.x, b.y, b.z, b.w};
#pragma unroll
        for (int i = 0; i < 8; ++i) {
          const float av = (kk == 0) ? ab[g & 3][i].x : (kk == 1) ? ab[g & 3][i].y
                         : (kk == 2) ? ab[g & 3][i].z : ab[g & 3][i].w;
#pragma unroll
          for (int j = 0; j < 4; ++j)
            acc[i][j] = __fmaf_rn(av, bbv[j], acc[i][j]);
        }
      }
    }
    if (c16 < 15) {
      // write next chunk into Bn; safe: all waves finished reading Bn before the
      // barrier that ended the previous chunk
      *(float4*)(Bn + bk * 260 + bl4)       = r0;
      *(float4*)(Bn + bk * 260 + bl4 + 128) = r1;
      const float* tmp = Bc; Bc = Bn; Bn = (float*)tmp;
    }
    __syncthreads();   // one barrier per chunk; final one guards the H alias below
  }

  // epilogue: bias + relu -> H[c][m] swizzled (unchanged, verified)
  const float4 bd = *(const float4*)(bd1 + (colT << 2));
  const float ba[4] = {bd.x, bd.y, bd.z, bd.w};
#pragma unroll
  for (int i = 0; i < 8; ++i) {
    const int m = (rowT << 3) + i;
#pragma unroll
    for (int j = 0; j < 4; ++j) {
      const int c = (colT << 2) + j;
      H[(c << 6) + (m ^ ((c >> 2) & 31))] = fmaxf(__fadd_rn(acc[i][j], ba[j]), 0.0f);
    }
  }
  __syncthreads();

  // w-chain: ascending-c single FMA chain; key = (w+bd2)/0.1f (unchanged, verified)
  if (t < 64) {
    float wa = 0.0f;
    for (int c = 0; c < 256; ++c)
      wa = __fmaf_rn(H[(c << 6) + (t ^ ((c >> 2) & 31))], Wd2[c], wa);
    const float w = __fadd_rn(wa, bd2[0]);
    wkey[m0 + t] = __fdiv_rn(w, 0.1f);
  }
}

// ---------------- per-batch top-K: u64-packed bitonic (key desc, tie: lower idx) ----------------
__global__ void __launch_bounds__(1024) topk_kernel(
    const float* __restrict__ wv, const float* __restrict__ xyzs,
    int* __restrict__ idx_out, float* __restrict__ out_xyz,
    float* __restrict__ out_idx) {
  __shared__ unsigned long long vals[2048];
  const int b = blockIdx.x, t = threadIdx.x;
#pragma unroll
  for (int h = 0; h < 2; ++h) {
    const int i = (h << 10) + t;
    const unsigned int u = __float_as_uint(wv[(b << 11) + i]);
    const unsigned int up = ((int)u < 0) ? ~u : (u | 0x80000000u);
    vals[i] = (((unsigned long long)(~up)) << 32) | (unsigned int)i;
  }
  __syncthreads();
  for (int k = 2; k <= 2048; k <<= 1) {
    for (int j = k >> 1; j > 0; j >>= 1) {
      for (int half = 0; half < 2; ++half) {
        const int i = (half << 10) | t;
        const int ixj = i ^ j;
        if (ixj > i) {
          const unsigned long long vi = vals[i], vj = vals[ixj];
          const bool up = ((i & k) == 0);
          if ((vi > vj) == up) { vals[i] = vj; vals[ixj] = vi; }
        }
      }
      __syncthreads();
    }
  }
  const int sel = (int)(vals[t] & 0xffffffffu);
  idx_out[(b << 10) + t] = sel;
  out_idx[(b << 10) + t] = (float)sel;
  const long o = ((long)((b << 10) + t)) * 3;
  const long s3 = ((long)((b << 11) + sel)) * 3;
  out_xyz[o] = xyzs[s3]; out_xyz[o + 1] = xyzs[s3 + 1]; out_xyz[o + 2] = xyzs[s3 + 2];
}

// ---------------- weight prep (merged): W (256x256 f32) -> P bf16 slabs [kc][n][32] ----------------
__global__ __launch_bounds__(256) void prep_w2(const float* __restrict__ W1,
    const float* __restrict__ W2, unsigned short* __restrict__ P1,
    unsigned short* __restrict__ P2) {
  const int g = blockIdx.x;
  const float* W = (g < 8) ? W1 : W2;
  unsigned short* P = (g < 8) ? P1 : P2;
  const int kc = g & 7, n = threadIdx.x;
  unsigned int packed[16];
#pragma unroll
  for (int i = 0; i < 16; ++i) {
    const float a = W[(((kc << 5) + 2 * i) << 8) + n];
    const float bq = W[(((kc << 5) + 2 * i + 1) << 8) + n];
    packed[i] = bf16rne(a) | (bf16rne(bq) << 16);
  }
  uint4* dst = (uint4*)(P + (((kc << 8) + n) << 5));
#pragma unroll
  for (int q = 0; q < 4; ++q)
    dst[q] = make_uint4(packed[4 * q], packed[4 * q + 1], packed[4 * q + 2], packed[4 * q + 3]);
}

// ---------------- fused up-branch: gather -> bf16 MFMA GEMM1(relu) -> GEMM2 -> transposed out ----------------
#define APITCH 264
#define BPITCH 40
__global__ void __launch_bounds__(256) up_mfma(
    const float* __restrict__ fbuf, const int* __restrict__ idxm,
    const unsigned short* __restrict__ Wu1P, const float* __restrict__ bu1,
    const unsigned short* __restrict__ Wu2P, const float* __restrict__ bu2,
    float* __restrict__ out_feat) {
  __shared__ __align__(16) char smem[64 * APITCH * 2 + 256 * BPITCH * 2 + 2048];
  unsigned short* As = (unsigned short*)smem;                       // 33792 B (later Hs)
  unsigned short* Bs = (unsigned short*)(smem + 64 * APITCH * 2);   // 20480 B (later T)
  float* bias1 = (float*)(smem + 64 * APITCH * 2 + 256 * BPITCH * 2);
  float* bias2 = bias1 + 256;
  float* T = (float*)(smem + 64 * APITCH * 2);                      // 64x66 f32 = 16896 B

  const int t = threadIdx.x;
  const int m0 = blockIdx.x << 6;
  const int quad = (t >> 4) & 3, ln = t & 15, w = t >> 6;

  bias1[t] = bu1[t];
  bias2[t] = bu2[t];

  // gather + cvt: As[r][c] bf16, r = t&63, cols (t>>6)*64..+63
  {
    const int r = t & 63, cseg = t >> 6;
    const int m = m0 + r;
    const long srow = (long)(((m >> 10) << 11) + idxm[m]) << 8;
    const float* src = fbuf + srow + (cseg << 6);
    unsigned short* dst = As + r * APITCH + (cseg << 6);
#pragma unroll
    for (int u = 0; u < 16; ++u) {
      const float4 v = *(const float4*)(src + (u << 2));
      const unsigned int lo = bf16rne(v.x) | (bf16rne(v.y) << 16);
      const unsigned int hi = bf16rne(v.z) | (bf16rne(v.w) << 16);
      *(uint2*)(dst + (u << 2)) = make_uint2(lo, hi);
    }
  }

  f32x4 acc[16];
#pragma unroll
  for (int i = 0; i < 16; ++i) acc[i] = (f32x4){0.f, 0.f, 0.f, 0.f};

  // ---- GEMM1: hu = gathered_f @ Wu1 ----
  for (int kc = 0; kc < 8; ++kc) {
    __syncthreads();
    const uint4* sb = (const uint4*)(Wu1P + (((kc << 8) + t) << 5));
    uint4* db = (uint4*)(Bs + t * BPITCH);
    db[0] = sb[0]; db[1] = sb[1]; db[2] = sb[2]; db[3] = sb[3];
    __syncthreads();
    const short8 a = *(const short8*)(As + ((w << 4) + ln) * APITCH + (kc << 5) + (quad << 3));
#pragma unroll
    for (int nt = 0; nt < 16; ++nt) {
      const short8 b = *(const short8*)(Bs + ((nt << 4) + ln) * BPITCH + (quad << 3));
      acc[nt] = __builtin_amdgcn_mfma_f32_16x16x32_bf16(a, b, acc[nt], 0, 0, 0);
    }
  }

  // ---- relu + bias -> Hs (alias As) ----
  __syncthreads();
  unsigned short* Hs = As;
#pragma unroll
  for (int nt = 0; nt < 16; ++nt) {
    const int c = (nt << 4) + ln;
    const float bb = bias1[c];
#pragma unroll
    for (int rr = 0; rr < 4; ++rr) {
      const float h = fmaxf(acc[nt][rr] + bb, 0.0f);
      Hs[((w << 4) + (quad << 2) + rr) * APITCH + c] = (unsigned short)bf16rne(h);
    }
  }
#pragma unroll
  for (int i = 0; i < 16; ++i) acc[i] = (f32x4){0.f, 0.f, 0.f, 0.f};

  // ---- GEMM2: nf = hu @ Wu2 ----
  for (int kc = 0; kc < 8; ++kc) {
    __syncthreads();
    const uint4* sb = (const uint4*)(Wu2P + (((kc << 8) + t) << 5));
    uint4* db = (uint4*)(Bs + t * BPITCH);
    db[0] = sb[0]; db[1] = sb[1]; db[2] = sb[2]; db[3] = sb[3];
    __syncthreads();
    const short8 a = *(const short8*)(Hs + ((w << 4) + ln) * APITCH + (kc << 5) + (quad << 3));
#pragma unroll
    for (int nt = 0; nt < 16; ++nt) {
      const short8 b = *(const short8*)(Bs + ((nt << 4) + ln) * BPITCH + (quad << 3));
      acc[nt] = __builtin_amdgcn_mfma_f32_16x16x32_bf16(a, b, acc[nt], 0, 0, 0);
    }
  }

  // ---- epilogue: +bu2, transpose via LDS, write out_feat (B,C,K) coalesced ----
  const int bb = m0 >> 10, kbase = m0 & 1023;
  for (int ci = 0; ci < 4; ++ci) {
    __syncthreads();
#pragma unroll
    for (int q = 0; q < 4; ++q) {
      const int nt = (ci << 2) + q;
      const int cloc = (q << 4) + ln;
      const float b2 = bias2[(nt << 4) + ln];
#pragma unroll
      for (int rr = 0; rr < 4; ++rr)
        T[cloc * 66 + ((w << 4) + (quad << 2) + rr)] = acc[nt][rr] + b2;
    }
    __syncthreads();
#pragma unroll
    for (int p = 0; p < 16; ++p) {
      const int cl = (p << 2) + (t >> 6);
      const int m = t & 63;
      out_feat[((long)((bb << 8) + (ci << 6) + cl) << 10) + kbase + m] = T[cl * 66 + m];
    }
  }
}

extern "C" void kernel_launch(void* const* d_in, const int* in_sizes, int n_in,
                              void* d_out, int out_size, void* d_ws, size_t ws_size,
                              hipStream_t stream) {
  const float* xyzs     = (const float*)d_in[0];
  const float* features = (const float*)d_in[1];
  const float* ln_gamma = (const float*)d_in[2];
  const float* ln_beta  = (const float*)d_in[3];
  const float* Wu1      = (const float*)d_in[4];
  const float* bu1      = (const float*)d_in[5];
  const float* Wu2      = (const float*)d_in[6];
  const float* bu2      = (const float*)d_in[7];
  const float* Wd1      = (const float*)d_in[8];
  const float* bd1      = (const float*)d_in[9];
  const float* Wd2      = (const float*)d_in[10];
  const float* bd2      = (const float*)d_in[11];

  char* ws = (char*)d_ws;
  float* fbuf = (float*)ws;                              // 16 MB
  unsigned short* Wu1P = (unsigned short*)(ws + 33554432);  // 128 KB bf16 slabs
  unsigned short* Wu2P = (unsigned short*)(ws + 33685504);  // 128 KB
  float* wv   = (float*)(ws + 50331648);                 // 16384 f32
  int*   idx  = (int*)(ws + 50397184);                   // 8192 i32

  float* out_xyz  = (float*)d_out;            // (8,1024,3)
  float* out_feat = out_xyz + 24576;          // (8,256,1024)
  float* out_idx  = out_feat + 2097152;       // (8,1024)

  prep_w2<<<16, 256, 0, stream>>>(Wu1, Wu2, Wu1P, Wu2P);
  ln_lds<<<256, 64, 0, stream>>>(features, ln_gamma, ln_beta, fbuf);
  wgemm_w<<<256, 512, 0, stream>>>(fbuf, Wd1, bd1, Wd2, bd2, wv);
  topk_kernel<<<8, 1024, 0, stream>>>(wv, xyzs, idx, out_xyz, out_idx);
  up_mfma<<<128, 256, 0, stream>>>(fbuf, idx, Wu1P, bu1, Wu2P, bu2, out_feat);
}

// Round 4
// 238.242 us; speedup vs baseline: 1.2808x; 1.2808x over previous
//
#include <hip/hip_runtime.h>

#define B_DIM 8
#define N_DIM 2048
#define C_DIM 256
#define K_SEL 1024

typedef __attribute__((ext_vector_type(8))) short short8;
typedef __attribute__((ext_vector_type(4))) float f32x4;

__device__ __forceinline__ unsigned int bf16rne(float x) {
  unsigned int u = __float_as_uint(x);
  return (u + 0x7fffu + ((u >> 16) & 1u)) >> 16;
}

// ---------------- LayerNorm, numpy-bit-exact, LDS-staged (unchanged, verified) ----------------
__global__ __launch_bounds__(64) void ln_lds(const float* __restrict__ feat,
    const float* __restrict__ gamma, const float* __restrict__ beta,
    float* __restrict__ fbuf) {
  __shared__ float tile[256 * 64];   // 64 KB exactly
  const int t = threadIdx.x;
  const int m0 = blockIdx.x << 6;
  const int b = m0 >> 11, n0 = m0 & 2047;

  const int cg = t >> 4, nl4 = (t & 15) << 2;
  for (int pass = 0; pass < 64; ++pass) {
    const int c = (pass << 2) + cg;
    const float4 v = *(const float4*)(feat + (((long)((b << 8) + c)) << 11) + n0 + nl4);
    const int sw = c & 31;
    float* row = tile + (c << 6);
    row[(nl4 + 0) ^ sw] = v.x; row[(nl4 + 1) ^ sw] = v.y;
    row[(nl4 + 2) ^ sw] = v.z; row[(nl4 + 3) ^ sw] = v.w;
  }
  __syncthreads();

  // mean: sequential ascending single chain (numpy strided-axis outer reduction)
  float acc = tile[t];
  for (int c = 1; c < 256; ++c) acc = __fadd_rn(acc, tile[(c << 6) + (t ^ (c & 31))]);
  const float mu = __fdiv_rn(acc, 256.0f);

  // var: numpy pairwise (2 halves x 8 accumulators) on contiguous (x-mu)^2
  float pw[2];
#pragma unroll
  for (int blk = 0; blk < 2; ++blk) {
    const int c0 = blk << 7;
    float r8[8];
#pragma unroll
    for (int j = 0; j < 8; ++j) {
      float d = __fsub_rn(tile[((c0 + j) << 6) + (t ^ ((c0 + j) & 31))], mu);
      r8[j] = __fmul_rn(d, d);
    }
    for (int i = 8; i < 128; i += 8) {
#pragma unroll
      for (int j = 0; j < 8; ++j) {
        const int c = c0 + i + j;
        float d = __fsub_rn(tile[(c << 6) + (t ^ (c & 31))], mu);
        r8[j] = __fadd_rn(r8[j], __fmul_rn(d, d));
      }
    }
    pw[blk] = __fadd_rn(__fadd_rn(__fadd_rn(r8[0], r8[1]), __fadd_rn(r8[2], r8[3])),
                        __fadd_rn(__fadd_rn(r8[4], r8[5]), __fadd_rn(r8[6], r8[7])));
  }
  const float var = __fdiv_rn(__fadd_rn(pw[0], pw[1]), 256.0f);
  const float rs = __fdiv_rn(1.0f, __fsqrt_rn(__fadd_rn(var, 1e-6f)));

  float ga[4], be[4];
#pragma unroll
  for (int q = 0; q < 4; ++q) { ga[q] = gamma[(q << 6) + t]; be[q] = beta[(q << 6) + t]; }
  for (int r = 0; r < 64; ++r) {
    const float mu_r = __shfl(mu, r, 64);
    const float rs_r = __shfl(rs, r, 64);
    float* orow = fbuf + (((long)(m0 + r)) << 8);
#pragma unroll
    for (int q = 0; q < 4; ++q) {
      const int c = (q << 6) + t;
      const float x = tile[(c << 6) + (r ^ (c & 31))];
      orow[c] = __fadd_rn(__fmul_rn(__fmul_rn(__fsub_rn(x, mu_r), rs_r), ga[q]), be[q]);
    }
  }
}

// ---------------- fused down-GEMM + w-chain, 512 threads (bit-exact chains) ----------------
// v5: A broadcast from global via opaque-lane vector loads (v4 proved loads go vector),
// but pipeline shrunk to TWO static float4[8] buffers (64 VGPRs, parity-indexed, no
// rotation copies). Live set ~120 regs < the 128-reg cap the allocator picks for 512t
// -> NO SPILL (v2/v4 failed purely on A-file footprint 128 regs -> ~50-reg spill,
// 24-409MB scratch WRITE_SIZE). Per kk per wave only 1 spanning B ds_read_b128 remains:
// per-CU LDS 96 cyc < per-SIMD VALU 128 cyc -> VALU-bound. Prefetch distance = 1 group
// (~256 SIMD-cyc issue, ~2x with wave interleave) covers L2/L3 latency of L3-resident fbuf.
// FMA chain per (m,c) stays ascending-k single chain -> bit-exact w (top-k safe).
__global__ void __launch_bounds__(512) wgemm_w(
    const float* __restrict__ A, const float* __restrict__ Wd1,
    const float* __restrict__ bd1, const float* __restrict__ Wd2,
    const float* __restrict__ bd2, float* __restrict__ wkey) {
  __shared__ __align__(16) char smem[65536];
  float* Bs0f = (float*)smem;                  // 16x260 f32 = 16640 B
  float* Bs1f = (float*)(smem + 16640);        // 16640 B (double buffer)
  float* H = (float*)smem;                     // 256x64 f32 = 64 KB (epilogue alias)

  const int t = threadIdx.x;
  const int m0 = blockIdx.x << 6;
  const int rowT = t >> 6, colT = t & 63;      // rowT uniform per wave
  const int bk = t >> 5, bl4 = (t & 31) << 2;  // staging: lane-consecutive float4s

  // opaque zero: defeats uniform-address scalar-load conversion (all lanes load the same
  // address -> one broadcast transaction, but via the vector pipe with counted vmcnt)
  int zero0 = 0;
  asm volatile("" : "+v"(zero0));
  const float* aw = A + ((long)(m0 + (rowT << 3)) << 8) + zero0;  // wave's 8 rows

  float acc[8][4] = {};

  // B prologue: stage chunk 0 into Bs0 (conflict-free: lanes write consecutive float4s)
  {
    const float* brow = Wd1 + (bk << 8);
    *(float4*)(Bs0f + bk * 260 + bl4)       = *(const float4*)(brow + bl4);
    *(float4*)(Bs0f + bk * 260 + bl4 + 128) = *(const float4*)(brow + bl4 + 128);
  }

  // A prologue: group 0 (k=0..3) into buffer 0
  float4 ab[2][8];
#pragma unroll
  for (int i = 0; i < 8; ++i) ab[0][i] = *(const float4*)(aw + (i << 8));

  __syncthreads();

  const float* Bc = Bs0f;
  float* Bn = Bs1f;
  for (int c16 = 0; c16 < 16; ++c16) {
    // issue next B-chunk global loads (wraps on last iter; then unused)
    float4 r0, r1;
    {
      const int knext = (c16 + 1) & 15;
      const float* brow = Wd1 + (((knext << 4) + bk) << 8);
      r0 = *(const float4*)(brow + bl4);
      r1 = *(const float4*)(brow + bl4 + 128);
    }
#pragma unroll
    for (int g = 0; g < 4; ++g) {               // group G = c16*4+g covers k=4G..4G+3
      // prefetch A for group G+1 into the other parity buffer (wraps at k=256; then unused)
      const int kpre = (((c16 << 2) + g + 1) << 2) & 255;
#pragma unroll
      for (int i = 0; i < 8; ++i)
        ab[(g + 1) & 1][i] = *(const float4*)(aw + (i << 8) + kpre);
#pragma unroll
      for (int kk = 0; kk < 4; ++kk) {          // k ascending: single FMA chain per (m,c)
        const float4 b = *(const float4*)(Bc + ((g << 2) + kk) * 260 + (colT << 2));
        const float bbv[4] = {b.x, b.y, b.z, b.w};
#pragma unroll
        for (int i = 0; i < 8; ++i) {
          const float av = (kk == 0) ? ab[g & 1][i].x : (kk == 1) ? ab[g & 1][i].y
                         : (kk == 2) ? ab[g & 1][i].z : ab[g & 1][i].w;
#pragma unroll
          for (int j = 0; j < 4; ++j)
            acc[i][j] = __fmaf_rn(av, bbv[j], acc[i][j]);
        }
      }
    }
    if (c16 < 15) {
      // write next chunk into Bn; safe: all waves finished reading Bn before the
      // barrier that ended the previous chunk
      *(float4*)(Bn + bk * 260 + bl4)       = r0;
      *(float4*)(Bn + bk * 260 + bl4 + 128) = r1;
      const float* tmp = Bc; Bc = Bn; Bn = (float*)tmp;
    }
    __syncthreads();   // one barrier per chunk; final one guards the H alias below
  }

  // epilogue: bias + relu -> H[c][m] swizzled (unchanged, verified)
  const float4 bd = *(const float4*)(bd1 + (colT << 2));
  const float ba[4] = {bd.x, bd.y, bd.z, bd.w};
#pragma unroll
  for (int i = 0; i < 8; ++i) {
    const int m = (rowT << 3) + i;
#pragma unroll
    for (int j = 0; j < 4; ++j) {
      const int c = (colT << 2) + j;
      H[(c << 6) + (m ^ ((c >> 2) & 31))] = fmaxf(__fadd_rn(acc[i][j], ba[j]), 0.0f);
    }
  }
  __syncthreads();

  // w-chain: ascending-c single FMA chain; key = (w+bd2)/0.1f (unchanged, verified)
  if (t < 64) {
    float wa = 0.0f;
    for (int c = 0; c < 256; ++c)
      wa = __fmaf_rn(H[(c << 6) + (t ^ ((c >> 2) & 31))], Wd2[c], wa);
    const float w = __fadd_rn(wa, bd2[0]);
    wkey[m0 + t] = __fdiv_rn(w, 0.1f);
  }
}

// ---------------- per-batch top-K: u64-packed bitonic (key desc, tie: lower idx) ----------------
__global__ void __launch_bounds__(1024) topk_kernel(
    const float* __restrict__ wv, const float* __restrict__ xyzs,
    int* __restrict__ idx_out, float* __restrict__ out_xyz,
    float* __restrict__ out_idx) {
  __shared__ unsigned long long vals[2048];
  const int b = blockIdx.x, t = threadIdx.x;
#pragma unroll
  for (int h = 0; h < 2; ++h) {
    const int i = (h << 10) + t;
    const unsigned int u = __float_as_uint(wv[(b << 11) + i]);
    const unsigned int up = ((int)u < 0) ? ~u : (u | 0x80000000u);
    vals[i] = (((unsigned long long)(~up)) << 32) | (unsigned int)i;
  }
  __syncthreads();
  for (int k = 2; k <= 2048; k <<= 1) {
    for (int j = k >> 1; j > 0; j >>= 1) {
      for (int half = 0; half < 2; ++half) {
        const int i = (half << 10) | t;
        const int ixj = i ^ j;
        if (ixj > i) {
          const unsigned long long vi = vals[i], vj = vals[ixj];
          const bool up = ((i & k) == 0);
          if ((vi > vj) == up) { vals[i] = vj; vals[ixj] = vi; }
        }
      }
      __syncthreads();
    }
  }
  const int sel = (int)(vals[t] & 0xffffffffu);
  idx_out[(b << 10) + t] = sel;
  out_idx[(b << 10) + t] = (float)sel;
  const long o = ((long)((b << 10) + t)) * 3;
  const long s3 = ((long)((b << 11) + sel)) * 3;
  out_xyz[o] = xyzs[s3]; out_xyz[o + 1] = xyzs[s3 + 1]; out_xyz[o + 2] = xyzs[s3 + 2];
}

// ---------------- weight prep (merged): W (256x256 f32) -> P bf16 slabs [kc][n][32] ----------------
__global__ __launch_bounds__(256) void prep_w2(const float* __restrict__ W1,
    const float* __restrict__ W2, unsigned short* __restrict__ P1,
    unsigned short* __restrict__ P2) {
  const int g = blockIdx.x;
  const float* W = (g < 8) ? W1 : W2;
  unsigned short* P = (g < 8) ? P1 : P2;
  const int kc = g & 7, n = threadIdx.x;
  unsigned int packed[16];
#pragma unroll
  for (int i = 0; i < 16; ++i) {
    const float a = W[(((kc << 5) + 2 * i) << 8) + n];
    const float bq = W[(((kc << 5) + 2 * i + 1) << 8) + n];
    packed[i] = bf16rne(a) | (bf16rne(bq) << 16);
  }
  uint4* dst = (uint4*)(P + (((kc << 8) + n) << 5));
#pragma unroll
  for (int q = 0; q < 4; ++q)
    dst[q] = make_uint4(packed[4 * q], packed[4 * q + 1], packed[4 * q + 2], packed[4 * q + 3]);
}

// ---------------- fused up-branch: gather -> bf16 MFMA GEMM1(relu) -> GEMM2 -> transposed out ----------------
#define APITCH 264
#define BPITCH 40
__global__ void __launch_bounds__(256) up_mfma(
    const float* __restrict__ fbuf, const int* __restrict__ idxm,
    const unsigned short* __restrict__ Wu1P, const float* __restrict__ bu1,
    const unsigned short* __restrict__ Wu2P, const float* __restrict__ bu2,
    float* __restrict__ out_feat) {
  __shared__ __align__(16) char smem[64 * APITCH * 2 + 256 * BPITCH * 2 + 2048];
  unsigned short* As = (unsigned short*)smem;                       // 33792 B (later Hs)
  unsigned short* Bs = (unsigned short*)(smem + 64 * APITCH * 2);   // 20480 B (later T)
  float* bias1 = (float*)(smem + 64 * APITCH * 2 + 256 * BPITCH * 2);
  float* bias2 = bias1 + 256;
  float* T = (float*)(smem + 64 * APITCH * 2);                      // 64x66 f32 = 16896 B

  const int t = threadIdx.x;
  const int m0 = blockIdx.x << 6;
  const int quad = (t >> 4) & 3, ln = t & 15, w = t >> 6;

  bias1[t] = bu1[t];
  bias2[t] = bu2[t];

  // gather + cvt: As[r][c] bf16, r = t&63, cols (t>>6)*64..+63
  {
    const int r = t & 63, cseg = t >> 6;
    const int m = m0 + r;
    const long srow = (long)(((m >> 10) << 11) + idxm[m]) << 8;
    const float* src = fbuf + srow + (cseg << 6);
    unsigned short* dst = As + r * APITCH + (cseg << 6);
#pragma unroll
    for (int u = 0; u < 16; ++u) {
      const float4 v = *(const float4*)(src + (u << 2));
      const unsigned int lo = bf16rne(v.x) | (bf16rne(v.y) << 16);
      const unsigned int hi = bf16rne(v.z) | (bf16rne(v.w) << 16);
      *(uint2*)(dst + (u << 2)) = make_uint2(lo, hi);
    }
  }

  f32x4 acc[16];
#pragma unroll
  for (int i = 0; i < 16; ++i) acc[i] = (f32x4){0.f, 0.f, 0.f, 0.f};

  // ---- GEMM1: hu = gathered_f @ Wu1 ----
  for (int kc = 0; kc < 8; ++kc) {
    __syncthreads();
    const uint4* sb = (const uint4*)(Wu1P + (((kc << 8) + t) << 5));
    uint4* db = (uint4*)(Bs + t * BPITCH);
    db[0] = sb[0]; db[1] = sb[1]; db[2] = sb[2]; db[3] = sb[3];
    __syncthreads();
    const short8 a = *(const short8*)(As + ((w << 4) + ln) * APITCH + (kc << 5) + (quad << 3));
#pragma unroll
    for (int nt = 0; nt < 16; ++nt) {
      const short8 b = *(const short8*)(Bs + ((nt << 4) + ln) * BPITCH + (quad << 3));
      acc[nt] = __builtin_amdgcn_mfma_f32_16x16x32_bf16(a, b, acc[nt], 0, 0, 0);
    }
  }

  // ---- relu + bias -> Hs (alias As) ----
  __syncthreads();
  unsigned short* Hs = As;
#pragma unroll
  for (int nt = 0; nt < 16; ++nt) {
    const int c = (nt << 4) + ln;
    const float bb = bias1[c];
#pragma unroll
    for (int rr = 0; rr < 4; ++rr) {
      const float h = fmaxf(acc[nt][rr] + bb, 0.0f);
      Hs[((w << 4) + (quad << 2) + rr) * APITCH + c] = (unsigned short)bf16rne(h);
    }
  }
#pragma unroll
  for (int i = 0; i < 16; ++i) acc[i] = (f32x4){0.f, 0.f, 0.f, 0.f};

  // ---- GEMM2: nf = hu @ Wu2 ----
  for (int kc = 0; kc < 8; ++kc) {
    __syncthreads();
    const uint4* sb = (const uint4*)(Wu2P + (((kc << 8) + t) << 5));
    uint4* db = (uint4*)(Bs + t * BPITCH);
    db[0] = sb[0]; db[1] = sb[1]; db[2] = sb[2]; db[3] = sb[3];
    __syncthreads();
    const short8 a = *(const short8*)(Hs + ((w << 4) + ln) * APITCH + (kc << 5) + (quad << 3));
#pragma unroll
    for (int nt = 0; nt < 16; ++nt) {
      const short8 b = *(const short8*)(Bs + ((nt << 4) + ln) * BPITCH + (quad << 3));
      acc[nt] = __builtin_amdgcn_mfma_f32_16x16x32_bf16(a, b, acc[nt], 0, 0, 0);
    }
  }

  // ---- epilogue: +bu2, transpose via LDS, write out_feat (B,C,K) coalesced ----
  const int bb = m0 >> 10, kbase = m0 & 1023;
  for (int ci = 0; ci < 4; ++ci) {
    __syncthreads();
#pragma unroll
    for (int q = 0; q < 4; ++q) {
      const int nt = (ci << 2) + q;
      const int cloc = (q << 4) + ln;
      const float b2 = bias2[(nt << 4) + ln];
#pragma unroll
      for (int rr = 0; rr < 4; ++rr)
        T[cloc * 66 + ((w << 4) + (quad << 2) + rr)] = acc[nt][rr] + b2;
    }
    __syncthreads();
#pragma unroll
    for (int p = 0; p < 16; ++p) {
      const int cl = (p << 2) + (t >> 6);
      const int m = t & 63;
      out_feat[((long)((bb << 8) + (ci << 6) + cl) << 10) + kbase + m] = T[cl * 66 + m];
    }
  }
}

extern "C" void kernel_launch(void* const* d_in, const int* in_sizes, int n_in,
                              void* d_out, int out_size, void* d_ws, size_t ws_size,
                              hipStream_t stream) {
  const float* xyzs     = (const float*)d_in[0];
  const float* features = (const float*)d_in[1];
  const float* ln_gamma = (const float*)d_in[2];
  const float* ln_beta  = (const float*)d_in[3];
  const float* Wu1      = (const float*)d_in[4];
  const float* bu1      = (const float*)d_in[5];
  const float* Wu2      = (const float*)d_in[6];
  const float* bu2      = (const float*)d_in[7];
  const float* Wd1      = (const float*)d_in[8];
  const float* bd1      = (const float*)d_in[9];
  const float* Wd2      = (const float*)d_in[10];
  const float* bd2      = (const float*)d_in[11];

  char* ws = (char*)d_ws;
  float* fbuf = (float*)ws;                              // 16 MB
  unsigned short* Wu1P = (unsigned short*)(ws + 33554432);  // 128 KB bf16 slabs
  unsigned short* Wu2P = (unsigned short*)(ws + 33685504);  // 128 KB
  float* wv   = (float*)(ws + 50331648);                 // 16384 f32
  int*   idx  = (int*)(ws + 50397184);                   // 8192 i32

  float* out_xyz  = (float*)d_out;            // (8,1024,3)
  float* out_feat = out_xyz + 24576;          // (8,256,1024)
  float* out_idx  = out_feat + 2097152;       // (8,1024)

  prep_w2<<<16, 256, 0, stream>>>(Wu1, Wu2, Wu1P, Wu2P);
  ln_lds<<<256, 64, 0, stream>>>(features, ln_gamma, ln_beta, fbuf);
  wgemm_w<<<256, 512, 0, stream>>>(fbuf, Wd1, bd1, Wd2, bd2, wv);
  topk_kernel<<<8, 1024, 0, stream>>>(wv, xyzs, idx, out_xyz, out_idx);
  up_mfma<<<128, 256, 0, stream>>>(fbuf, idx, Wu1P, bu1, Wu2P, bu2, out_feat);
}

// Round 5
// 187.730 us; speedup vs baseline: 1.6254x; 1.2691x over previous
//
#include <hip/hip_runtime.h>

#define B_DIM 8
#define N_DIM 2048
#define C_DIM 256
#define K_SEL 1024

typedef __attribute__((ext_vector_type(8))) short short8;
typedef __attribute__((ext_vector_type(4))) float f32x4;

__device__ __forceinline__ unsigned int bf16rne(float x) {
  unsigned int u = __float_as_uint(x);
  return (u + 0x7fffu + ((u >> 16) & 1u)) >> 16;
}

// ---------------- LayerNorm, numpy-bit-exact, LDS-staged ----------------
// v6: widened 64 -> 256 threads. Staging 4x wider (identical tile contents),
// mean/var verbatim on t<64 (numpy-exact chains untouched), mu/rs published via LDS,
// epilogue 4x wider with float4 coalesced stores (same per-element arithmetic).
__global__ __launch_bounds__(256) void ln_lds(const float* __restrict__ feat,
    const float* __restrict__ gamma, const float* __restrict__ beta,
    float* __restrict__ fbuf) {
  __shared__ float tile[256 * 64];   // 64 KB
  __shared__ float murs[128];        // mu[0:64], rs[64:128]
  const int t = threadIdx.x;
  const int m0 = blockIdx.x << 6;
  const int b = m0 >> 11, n0 = m0 & 2047;

  // staging: 256 threads, 16 passes (was 64 passes with 64 threads); same (c,nl4) map
  const int cg = t >> 4, nl4 = (t & 15) << 2;   // cg in 0..15
  for (int pass = 0; pass < 16; ++pass) {
    const int c = (pass << 4) + cg;
    const float4 v = *(const float4*)(feat + (((long)((b << 8) + c)) << 11) + n0 + nl4);
    const int sw = c & 31;
    float* row = tile + (c << 6);
    row[(nl4 + 0) ^ sw] = v.x; row[(nl4 + 1) ^ sw] = v.y;
    row[(nl4 + 2) ^ sw] = v.z; row[(nl4 + 3) ^ sw] = v.w;
  }
  __syncthreads();

  if (t < 64) {
    // mean: sequential ascending single chain (numpy strided-axis outer reduction)
    float acc = tile[t];
    for (int c = 1; c < 256; ++c) acc = __fadd_rn(acc, tile[(c << 6) + (t ^ (c & 31))]);
    const float mu = __fdiv_rn(acc, 256.0f);

    // var: numpy pairwise (2 halves x 8 accumulators) on contiguous (x-mu)^2
    float pw[2];
#pragma unroll
    for (int blk = 0; blk < 2; ++blk) {
      const int c0 = blk << 7;
      float r8[8];
#pragma unroll
      for (int j = 0; j < 8; ++j) {
        float d = __fsub_rn(tile[((c0 + j) << 6) + (t ^ ((c0 + j) & 31))], mu);
        r8[j] = __fmul_rn(d, d);
      }
      for (int i = 8; i < 128; i += 8) {
#pragma unroll
        for (int j = 0; j < 8; ++j) {
          const int c = c0 + i + j;
          float d = __fsub_rn(tile[(c << 6) + (t ^ (c & 31))], mu);
          r8[j] = __fadd_rn(r8[j], __fmul_rn(d, d));
        }
      }
      pw[blk] = __fadd_rn(__fadd_rn(__fadd_rn(r8[0], r8[1]), __fadd_rn(r8[2], r8[3])),
                          __fadd_rn(__fadd_rn(r8[4], r8[5]), __fadd_rn(r8[6], r8[7])));
    }
    const float var = __fdiv_rn(__fadd_rn(pw[0], pw[1]), 256.0f);
    const float rs = __fdiv_rn(1.0f, __fsqrt_rn(__fadd_rn(var, 1e-6f)));
    murs[t] = mu;
    murs[64 + t] = rs;
  }
  __syncthreads();

  // epilogue: 256 threads; thread handles 4 CONSECUTIVE cols -> float4 stores.
  // per-element expression identical to verified version.
  const int tc = t & 63, rg = t >> 6;
  const int c0 = tc << 2;
  const float4 g4 = *(const float4*)(gamma + c0);
  const float4 b4 = *(const float4*)(beta + c0);
  const float ga[4] = {g4.x, g4.y, g4.z, g4.w};
  const float be[4] = {b4.x, b4.y, b4.z, b4.w};
  for (int rr = 0; rr < 16; ++rr) {
    const int r = (rg << 4) + rr;
    const float mu_r = murs[r];
    const float rs_r = murs[64 + r];
    float4 o;
    float ov[4];
#pragma unroll
    for (int q = 0; q < 4; ++q) {
      const int c = c0 + q;
      const float x = tile[(c << 6) + (r ^ (c & 31))];
      ov[q] = __fadd_rn(__fmul_rn(__fmul_rn(__fsub_rn(x, mu_r), rs_r), ga[q]), be[q]);
    }
    o.x = ov[0]; o.y = ov[1]; o.z = ov[2]; o.w = ov[3];
    *(float4*)(fbuf + (((long)(m0 + r)) << 8) + c0) = o;
  }
}

// ---------------- fused down-GEMM + w-chain, 512 threads (round-0 verified version) ----------------
// 64 rows x 256 cols, 8x4 acc. H in [c][m] layout, swizzle H[c*64 + (m ^ ((c>>2)&31))]:
// epilogue writes (lanes span colT) and w-chain reads (lanes span m) both hit 32 banks.
// NOTE: v2-v5 tried moving A out of LDS into registers (broadcast global loads). All
// variants spilled (compiler caps 512t blocks at 128 VGPR; A-pipeline needs 64-128 regs
// on top of 32 acc) -> scratch traffic 24-409MB, 2-4x slower. Reverted to this version.
__global__ void __launch_bounds__(512) wgemm_w(
    const float* __restrict__ A, const float* __restrict__ Wd1,
    const float* __restrict__ bd1, const float* __restrict__ Wd2,
    const float* __restrict__ bd2, float* __restrict__ wkey) {
  __shared__ __align__(16) char smem[65536];
  float (*As)[68] = (float (*)[68])smem;               // 16x68x4 = 4352 B
  float (*Bs)[260] = (float (*)[260])(smem + 4352);    // 16x260x4 = 16640 B
  float* H = (float*)smem;                              // 256x64 f32 = 64 KB (aliased)

  const int t = threadIdx.x;
  const int m0 = blockIdx.x << 6;
  const int rowT = t >> 6, colT = t & 63;
  const int ar = t >> 2, ak = (t & 3) << 2;             // A loaders: t<256
  const int bk = t >> 5, bc = (t & 31) << 3;            // B loaders: all 512
  const long arow = ((long)(m0 + ar)) << 8;
  float acc[8][4] = {};

  for (int k0 = 0; k0 < 256; k0 += 16) {
    if (t < 256) {
      const float4 av = *(const float4*)(A + arow + k0 + ak);
      As[ak + 0][ar] = av.x; As[ak + 1][ar] = av.y;
      As[ak + 2][ar] = av.z; As[ak + 3][ar] = av.w;
    }
    const float* brow = Wd1 + (((k0 + bk) << 8) + bc);
    *(float4*)&Bs[bk][bc] = *(const float4*)brow;
    *(float4*)&Bs[bk][bc + 4] = *(const float4*)(brow + 4);
    __syncthreads();
#pragma unroll
    for (int kk = 0; kk < 16; ++kk) {   // k ascending: single FMA chain per (m,c)
      const float4 a0 = *(const float4*)&As[kk][rowT << 3];
      const float4 a1 = *(const float4*)&As[kk][(rowT << 3) + 4];
      const float4 b = *(const float4*)&Bs[kk][colT << 2];
      const float aa[8] = {a0.x, a0.y, a0.z, a0.w, a1.x, a1.y, a1.z, a1.w};
      const float bbv[4] = {b.x, b.y, b.z, b.w};
#pragma unroll
      for (int i = 0; i < 8; ++i)
#pragma unroll
        for (int j = 0; j < 4; ++j)
          acc[i][j] = __fmaf_rn(aa[i], bbv[j], acc[i][j]);
    }
    __syncthreads();
  }

  // epilogue: bias + relu -> H[c][m] swizzled
  const float4 bd = *(const float4*)(bd1 + (colT << 2));
  const float ba[4] = {bd.x, bd.y, bd.z, bd.w};
#pragma unroll
  for (int i = 0; i < 8; ++i) {
    const int m = (rowT << 3) + i;
#pragma unroll
    for (int j = 0; j < 4; ++j) {
      const int c = (colT << 2) + j;
      H[(c << 6) + (m ^ ((c >> 2) & 31))] = fmaxf(__fadd_rn(acc[i][j], ba[j]), 0.0f);
    }
  }
  __syncthreads();

  // w-chain: ascending-c single FMA chain; key = (w+bd2)/0.1f
  if (t < 64) {
    float wa = 0.0f;
    for (int c = 0; c < 256; ++c)
      wa = __fmaf_rn(H[(c << 6) + (t ^ ((c >> 2) & 31))], Wd2[c], wa);
    const float w = __fadd_rn(wa, bd2[0]);
    wkey[m0 + t] = __fdiv_rn(w, 0.1f);
  }
}

// ---------------- per-batch top-K: u64-packed bitonic (key desc, tie: lower idx) ----------------
__global__ void __launch_bounds__(1024) topk_kernel(
    const float* __restrict__ wv, const float* __restrict__ xyzs,
    int* __restrict__ idx_out, float* __restrict__ out_xyz,
    float* __restrict__ out_idx) {
  __shared__ unsigned long long vals[2048];
  const int b = blockIdx.x, t = threadIdx.x;
#pragma unroll
  for (int h = 0; h < 2; ++h) {
    const int i = (h << 10) + t;
    const unsigned int u = __float_as_uint(wv[(b << 11) + i]);
    const unsigned int up = ((int)u < 0) ? ~u : (u | 0x80000000u);
    vals[i] = (((unsigned long long)(~up)) << 32) | (unsigned int)i;
  }
  __syncthreads();
  for (int k = 2; k <= 2048; k <<= 1) {
    for (int j = k >> 1; j > 0; j >>= 1) {
      for (int half = 0; half < 2; ++half) {
        const int i = (half << 10) | t;
        const int ixj = i ^ j;
        if (ixj > i) {
          const unsigned long long vi = vals[i], vj = vals[ixj];
          const bool up = ((i & k) == 0);
          if ((vi > vj) == up) { vals[i] = vj; vals[ixj] = vi; }
        }
      }
      __syncthreads();
    }
  }
  const int sel = (int)(vals[t] & 0xffffffffu);
  idx_out[(b << 10) + t] = sel;
  out_idx[(b << 10) + t] = (float)sel;
  const long o = ((long)((b << 10) + t)) * 3;
  const long s3 = ((long)((b << 11) + sel)) * 3;
  out_xyz[o] = xyzs[s3]; out_xyz[o + 1] = xyzs[s3 + 1]; out_xyz[o + 2] = xyzs[s3 + 2];
}

// ---------------- weight prep (merged): W (256x256 f32) -> P bf16 slabs [kc][n][32] ----------------
__global__ __launch_bounds__(256) void prep_w2(const float* __restrict__ W1,
    const float* __restrict__ W2, unsigned short* __restrict__ P1,
    unsigned short* __restrict__ P2) {
  const int g = blockIdx.x;
  const float* W = (g < 8) ? W1 : W2;
  unsigned short* P = (g < 8) ? P1 : P2;
  const int kc = g & 7, n = threadIdx.x;
  unsigned int packed[16];
#pragma unroll
  for (int i = 0; i < 16; ++i) {
    const float a = W[(((kc << 5) + 2 * i) << 8) + n];
    const float bq = W[(((kc << 5) + 2 * i + 1) << 8) + n];
    packed[i] = bf16rne(a) | (bf16rne(bq) << 16);
  }
  uint4* dst = (uint4*)(P + (((kc << 8) + n) << 5));
#pragma unroll
  for (int q = 0; q < 4; ++q)
    dst[q] = make_uint4(packed[4 * q], packed[4 * q + 1], packed[4 * q + 2], packed[4 * q + 3]);
}

// ---------------- fused up-branch: gather -> bf16 MFMA GEMM1(relu) -> GEMM2 -> transposed out ----------------
#define APITCH 264
#define BPITCH 40
__global__ void __launch_bounds__(256) up_mfma(
    const float* __restrict__ fbuf, const int* __restrict__ idxm,
    const unsigned short* __restrict__ Wu1P, const float* __restrict__ bu1,
    const unsigned short* __restrict__ Wu2P, const float* __restrict__ bu2,
    float* __restrict__ out_feat) {
  __shared__ __align__(16) char smem[64 * APITCH * 2 + 256 * BPITCH * 2 + 2048];
  unsigned short* As = (unsigned short*)smem;                       // 33792 B (later Hs)
  unsigned short* Bs = (unsigned short*)(smem + 64 * APITCH * 2);   // 20480 B (later T)
  float* bias1 = (float*)(smem + 64 * APITCH * 2 + 256 * BPITCH * 2);
  float* bias2 = bias1 + 256;
  float* T = (float*)(smem + 64 * APITCH * 2);                      // 64x66 f32 = 16896 B

  const int t = threadIdx.x;
  const int m0 = blockIdx.x << 6;
  const int quad = (t >> 4) & 3, ln = t & 15, w = t >> 6;

  bias1[t] = bu1[t];
  bias2[t] = bu2[t];

  // gather + cvt: As[r][c] bf16, r = t&63, cols (t>>6)*64..+63
  {
    const int r = t & 63, cseg = t >> 6;
    const int m = m0 + r;
    const long srow = (long)(((m >> 10) << 11) + idxm[m]) << 8;
    const float* src = fbuf + srow + (cseg << 6);
    unsigned short* dst = As + r * APITCH + (cseg << 6);
#pragma unroll
    for (int u = 0; u < 16; ++u) {
      const float4 v = *(const float4*)(src + (u << 2));
      const unsigned int lo = bf16rne(v.x) | (bf16rne(v.y) << 16);
      const unsigned int hi = bf16rne(v.z) | (bf16rne(v.w) << 16);
      *(uint2*)(dst + (u << 2)) = make_uint2(lo, hi);
    }
  }

  f32x4 acc[16];
#pragma unroll
  for (int i = 0; i < 16; ++i) acc[i] = (f32x4){0.f, 0.f, 0.f, 0.f};

  // ---- GEMM1: hu = gathered_f @ Wu1 ----
  for (int kc = 0; kc < 8; ++kc) {
    __syncthreads();
    const uint4* sb = (const uint4*)(Wu1P + (((kc << 8) + t) << 5));
    uint4* db = (uint4*)(Bs + t * BPITCH);
    db[0] = sb[0]; db[1] = sb[1]; db[2] = sb[2]; db[3] = sb[3];
    __syncthreads();
    const short8 a = *(const short8*)(As + ((w << 4) + ln) * APITCH + (kc << 5) + (quad << 3));
#pragma unroll
    for (int nt = 0; nt < 16; ++nt) {
      const short8 b = *(const short8*)(Bs + ((nt << 4) + ln) * BPITCH + (quad << 3));
      acc[nt] = __builtin_amdgcn_mfma_f32_16x16x32_bf16(a, b, acc[nt], 0, 0, 0);
    }
  }

  // ---- relu + bias -> Hs (alias As) ----
  __syncthreads();
  unsigned short* Hs = As;
#pragma unroll
  for (int nt = 0; nt < 16; ++nt) {
    const int c = (nt << 4) + ln;
    const float bb = bias1[c];
#pragma unroll
    for (int rr = 0; rr < 4; ++rr) {
      const float h = fmaxf(acc[nt][rr] + bb, 0.0f);
      Hs[((w << 4) + (quad << 2) + rr) * APITCH + c] = (unsigned short)bf16rne(h);
    }
  }
#pragma unroll
  for (int i = 0; i < 16; ++i) acc[i] = (f32x4){0.f, 0.f, 0.f, 0.f};

  // ---- GEMM2: nf = hu @ Wu2 ----
  for (int kc = 0; kc < 8; ++kc) {
    __syncthreads();
    const uint4* sb = (const uint4*)(Wu2P + (((kc << 8) + t) << 5));
    uint4* db = (uint4*)(Bs + t * BPITCH);
    db[0] = sb[0]; db[1] = sb[1]; db[2] = sb[2]; db[3] = sb[3];
    __syncthreads();
    const short8 a = *(const short8*)(Hs + ((w << 4) + ln) * APITCH + (kc << 5) + (quad << 3));
#pragma unroll
    for (int nt = 0; nt < 16; ++nt) {
      const short8 b = *(const short8*)(Bs + ((nt << 4) + ln) * BPITCH + (quad << 3));
      acc[nt] = __builtin_amdgcn_mfma_f32_16x16x32_bf16(a, b, acc[nt], 0, 0, 0);
    }
  }

  // ---- epilogue: +bu2, transpose via LDS, write out_feat (B,C,K) coalesced ----
  const int bb = m0 >> 10, kbase = m0 & 1023;
  for (int ci = 0; ci < 4; ++ci) {
    __syncthreads();
#pragma unroll
    for (int q = 0; q < 4; ++q) {
      const int nt = (ci << 2) + q;
      const int cloc = (q << 4) + ln;
      const float b2 = bias2[(nt << 4) + ln];
#pragma unroll
      for (int rr = 0; rr < 4; ++rr)
        T[cloc * 66 + ((w << 4) + (quad << 2) + rr)] = acc[nt][rr] + b2;
    }
    __syncthreads();
#pragma unroll
    for (int p = 0; p < 16; ++p) {
      const int cl = (p << 2) + (t >> 6);
      const int m = t & 63;
      out_feat[((long)((bb << 8) + (ci << 6) + cl) << 10) + kbase + m] = T[cl * 66 + m];
    }
  }
}

extern "C" void kernel_launch(void* const* d_in, const int* in_sizes, int n_in,
                              void* d_out, int out_size, void* d_ws, size_t ws_size,
                              hipStream_t stream) {
  const float* xyzs     = (const float*)d_in[0];
  const float* features = (const float*)d_in[1];
  const float* ln_gamma = (const float*)d_in[2];
  const float* ln_beta  = (const float*)d_in[3];
  const float* Wu1      = (const float*)d_in[4];
  const float* bu1      = (const float*)d_in[5];
  const float* Wu2      = (const float*)d_in[6];
  const float* bu2      = (const float*)d_in[7];
  const float* Wd1      = (const float*)d_in[8];
  const float* bd1      = (const float*)d_in[9];
  const float* Wd2      = (const float*)d_in[10];
  const float* bd2      = (const float*)d_in[11];

  char* ws = (char*)d_ws;
  float* fbuf = (float*)ws;                              // 16 MB
  unsigned short* Wu1P = (unsigned short*)(ws + 33554432);  // 128 KB bf16 slabs
  unsigned short* Wu2P = (unsigned short*)(ws + 33685504);  // 128 KB
  float* wv   = (float*)(ws + 50331648);                 // 16384 f32
  int*   idx  = (int*)(ws + 50397184);                   // 8192 i32

  float* out_xyz  = (float*)d_out;            // (8,1024,3)
  float* out_feat = out_xyz + 24576;          // (8,256,1024)
  float* out_idx  = out_feat + 2097152;       // (8,1024)

  prep_w2<<<16, 256, 0, stream>>>(Wu1, Wu2, Wu1P, Wu2P);
  ln_lds<<<256, 256, 0, stream>>>(features, ln_gamma, ln_beta, fbuf);
  wgemm_w<<<256, 512, 0, stream>>>(fbuf, Wd1, bd1, Wd2, bd2, wv);
  topk_kernel<<<8, 1024, 0, stream>>>(wv, xyzs, idx, out_xyz, out_idx);
  up_mfma<<<128, 256, 0, stream>>>(fbuf, idx, Wu1P, bu1, Wu2P, bu2, out_feat);
}

// Round 6
// 187.583 us; speedup vs baseline: 1.6267x; 1.0008x over previous
//
#include <hip/hip_runtime.h>

#define B_DIM 8
#define N_DIM 2048
#define C_DIM 256
#define K_SEL 1024

typedef __attribute__((ext_vector_type(8))) short short8;
typedef __attribute__((ext_vector_type(4))) float f32x4;

__device__ __forceinline__ unsigned int bf16rne(float x) {
  unsigned int u = __float_as_uint(x);
  return (u + 0x7fffu + ((u >> 16) & 1u)) >> 16;
}

// ---------------- LayerNorm, numpy-bit-exact, LDS-staged (v6 widened, verified) ----------------
__global__ __launch_bounds__(256) void ln_lds(const float* __restrict__ feat,
    const float* __restrict__ gamma, const float* __restrict__ beta,
    float* __restrict__ fbuf) {
  __shared__ float tile[256 * 64];   // 64 KB
  __shared__ float murs[128];        // mu[0:64], rs[64:128]
  const int t = threadIdx.x;
  const int m0 = blockIdx.x << 6;
  const int b = m0 >> 11, n0 = m0 & 2047;

  const int cg = t >> 4, nl4 = (t & 15) << 2;   // cg in 0..15
  for (int pass = 0; pass < 16; ++pass) {
    const int c = (pass << 4) + cg;
    const float4 v = *(const float4*)(feat + (((long)((b << 8) + c)) << 11) + n0 + nl4);
    const int sw = c & 31;
    float* row = tile + (c << 6);
    row[(nl4 + 0) ^ sw] = v.x; row[(nl4 + 1) ^ sw] = v.y;
    row[(nl4 + 2) ^ sw] = v.z; row[(nl4 + 3) ^ sw] = v.w;
  }
  __syncthreads();

  if (t < 64) {
    // mean: sequential ascending single chain (numpy strided-axis outer reduction)
    float acc = tile[t];
    for (int c = 1; c < 256; ++c) acc = __fadd_rn(acc, tile[(c << 6) + (t ^ (c & 31))]);
    const float mu = __fdiv_rn(acc, 256.0f);

    // var: numpy pairwise (2 halves x 8 accumulators) on contiguous (x-mu)^2
    float pw[2];
#pragma unroll
    for (int blk = 0; blk < 2; ++blk) {
      const int c0 = blk << 7;
      float r8[8];
#pragma unroll
      for (int j = 0; j < 8; ++j) {
        float d = __fsub_rn(tile[((c0 + j) << 6) + (t ^ ((c0 + j) & 31))], mu);
        r8[j] = __fmul_rn(d, d);
      }
      for (int i = 8; i < 128; i += 8) {
#pragma unroll
        for (int j = 0; j < 8; ++j) {
          const int c = c0 + i + j;
          float d = __fsub_rn(tile[(c << 6) + (t ^ (c & 31))], mu);
          r8[j] = __fadd_rn(r8[j], __fmul_rn(d, d));
        }
      }
      pw[blk] = __fadd_rn(__fadd_rn(__fadd_rn(r8[0], r8[1]), __fadd_rn(r8[2], r8[3])),
                          __fadd_rn(__fadd_rn(r8[4], r8[5]), __fadd_rn(r8[6], r8[7])));
    }
    const float var = __fdiv_rn(__fadd_rn(pw[0], pw[1]), 256.0f);
    const float rs = __fdiv_rn(1.0f, __fsqrt_rn(__fadd_rn(var, 1e-6f)));
    murs[t] = mu;
    murs[64 + t] = rs;
  }
  __syncthreads();

  const int tc = t & 63, rg = t >> 6;
  const int c0 = tc << 2;
  const float4 g4 = *(const float4*)(gamma + c0);
  const float4 b4 = *(const float4*)(beta + c0);
  const float ga[4] = {g4.x, g4.y, g4.z, g4.w};
  const float be[4] = {b4.x, b4.y, b4.z, b4.w};
  for (int rr = 0; rr < 16; ++rr) {
    const int r = (rg << 4) + rr;
    const float mu_r = murs[r];
    const float rs_r = murs[64 + r];
    float4 o;
    float ov[4];
#pragma unroll
    for (int q = 0; q < 4; ++q) {
      const int c = c0 + q;
      const float x = tile[(c << 6) + (r ^ (c & 31))];
      ov[q] = __fadd_rn(__fmul_rn(__fmul_rn(__fsub_rn(x, mu_r), rs_r), ga[q]), be[q]);
    }
    o.x = ov[0]; o.y = ov[1]; o.z = ov[2]; o.w = ov[3];
    *(float4*)(fbuf + (((long)(m0 + r)) << 8) + c0) = o;
  }
}

// ---------------- fused down-GEMM + w-chain, 512 threads (bit-exact chains) ----------------
// v7: A operand via wave-level lane-distribution + v_readlane broadcast.
// Per 32-k chunk, ONE global_load_dwordx4 per wave fetches A[8 rows][32 k]
// (lane l: row l&7, k-group l>>3 -> 8x128B coalesced segments). The uniform A[i][k]
// needed by the FMA is produced by __builtin_amdgcn_readlane (compile-time lane index,
// v_readlane -> SGPR; FMA takes 1 SGPR operand). Pure bit-move: FMA chain order and
// values identical to round-0 -> bit-exact w, top-k safe.
// LDS per kk per wave drops 3 ds_read_b128 -> 1 (B only): per-CU LDS 96 cyc < VALU
// 160 cyc -> VALU-bound. Register cost: acc 32 + 2 chunk bufs (8) -> ~64 VGPR, no spill
// (v2-v5 spilled because A was per-THREAD in registers: 64-128 regs).
// B staging uses v5's conflict-free lane map (measured 0 conflicts; values identical).
__global__ void __launch_bounds__(512) wgemm_w(
    const float* __restrict__ A, const float* __restrict__ Wd1,
    const float* __restrict__ bd1, const float* __restrict__ Wd2,
    const float* __restrict__ bd2, float* __restrict__ wkey) {
  __shared__ __align__(16) char smem[65536];
  float (*Bs)[260] = (float (*)[260])smem;             // 16x260x4 = 16640 B
  float* H = (float*)smem;                              // 256x64 f32 = 64 KB (aliased)

  const int t = threadIdx.x;
  const int m0 = blockIdx.x << 6;
  const int rowT = t >> 6, colT = t & 63;
  const int lane = t & 63;
  const int bk = t >> 5, bl4 = (t & 31) << 2;           // B staging: lane-consecutive float4s
  // wave's A slab: lane l covers row (rowT*8 + (l&7)), k-offset (l>>3)*4 within chunk
  const float* aload = A + ((long)(m0 + (rowT << 3) + (lane & 7)) << 8) + ((lane >> 3) << 2);

  float acc[8][4] = {};

  float4 ac = *(const float4*)(aload);                  // chunk 0: k = 0..31 lane-distributed

  for (int ch = 0; ch < 8; ++ch) {
    const int chn = (ch < 7) ? ch + 1 : 7;
    const float4 an = *(const float4*)(aload + (chn << 5));  // prefetch next chunk
#pragma unroll
    for (int h = 0; h < 2; ++h) {
      const int k0 = (ch << 5) + (h << 4);
      // stage B rows k0..k0+15 (conflict-free map, verified v5)
      {
        const float* brow = Wd1 + ((k0 + bk) << 8);
        *(float4*)&Bs[bk][bl4]       = *(const float4*)(brow + bl4);
        *(float4*)&Bs[bk][bl4 + 128] = *(const float4*)(brow + bl4 + 128);
      }
      __syncthreads();
#pragma unroll
      for (int kk = 0; kk < 16; ++kk) {   // k ascending: single FMA chain per (m,c)
        const int kkl = (h << 4) + kk;    // 0..31 within chunk (compile-time)
        const float4 b = *(const float4*)&Bs[kk][colT << 2];
        const float bbv[4] = {b.x, b.y, b.z, b.w};
        const float av_src = (kkl & 3) == 0 ? ac.x : (kkl & 3) == 1 ? ac.y
                           : (kkl & 3) == 2 ? ac.z : ac.w;
#pragma unroll
        for (int i = 0; i < 8; ++i) {
          const float aval = __uint_as_float(__builtin_amdgcn_readlane(
              __float_as_uint(av_src), ((kkl >> 2) << 3) + i));
#pragma unroll
          for (int j = 0; j < 4; ++j)
            acc[i][j] = __fmaf_rn(aval, bbv[j], acc[i][j]);
        }
      }
      __syncthreads();
    }
    ac = an;
  }

  // epilogue: bias + relu -> H[c][m] swizzled (unchanged, verified)
  const float4 bd = *(const float4*)(bd1 + (colT << 2));
  const float ba[4] = {bd.x, bd.y, bd.z, bd.w};
#pragma unroll
  for (int i = 0; i < 8; ++i) {
    const int m = (rowT << 3) + i;
#pragma unroll
    for (int j = 0; j < 4; ++j) {
      const int c = (colT << 2) + j;
      H[(c << 6) + (m ^ ((c >> 2) & 31))] = fmaxf(__fadd_rn(acc[i][j], ba[j]), 0.0f);
    }
  }
  __syncthreads();

  // w-chain: ascending-c single FMA chain; key = (w+bd2)/0.1f (unchanged, verified)
  if (t < 64) {
    float wa = 0.0f;
    for (int c = 0; c < 256; ++c)
      wa = __fmaf_rn(H[(c << 6) + (t ^ ((c >> 2) & 31))], Wd2[c], wa);
    const float w = __fadd_rn(wa, bd2[0]);
    wkey[m0 + t] = __fdiv_rn(w, 0.1f);
  }
}

// ---------------- per-batch top-K: u64-packed bitonic (key desc, tie: lower idx) ----------------
__global__ void __launch_bounds__(1024) topk_kernel(
    const float* __restrict__ wv, const float* __restrict__ xyzs,
    int* __restrict__ idx_out, float* __restrict__ out_xyz,
    float* __restrict__ out_idx) {
  __shared__ unsigned long long vals[2048];
  const int b = blockIdx.x, t = threadIdx.x;
#pragma unroll
  for (int h = 0; h < 2; ++h) {
    const int i = (h << 10) + t;
    const unsigned int u = __float_as_uint(wv[(b << 11) + i]);
    const unsigned int up = ((int)u < 0) ? ~u : (u | 0x80000000u);
    vals[i] = (((unsigned long long)(~up)) << 32) | (unsigned int)i;
  }
  __syncthreads();
  for (int k = 2; k <= 2048; k <<= 1) {
    for (int j = k >> 1; j > 0; j >>= 1) {
      for (int half = 0; half < 2; ++half) {
        const int i = (half << 10) | t;
        const int ixj = i ^ j;
        if (ixj > i) {
          const unsigned long long vi = vals[i], vj = vals[ixj];
          const bool up = ((i & k) == 0);
          if ((vi > vj) == up) { vals[i] = vj; vals[ixj] = vi; }
        }
      }
      __syncthreads();
    }
  }
  const int sel = (int)(vals[t] & 0xffffffffu);
  idx_out[(b << 10) + t] = sel;
  out_idx[(b << 10) + t] = (float)sel;
  const long o = ((long)((b << 10) + t)) * 3;
  const long s3 = ((long)((b << 11) + sel)) * 3;
  out_xyz[o] = xyzs[s3]; out_xyz[o + 1] = xyzs[s3 + 1]; out_xyz[o + 2] = xyzs[s3 + 2];
}

// ---------------- weight prep (merged): W (256x256 f32) -> P bf16 slabs [kc][n][32] ----------------
__global__ __launch_bounds__(256) void prep_w2(const float* __restrict__ W1,
    const float* __restrict__ W2, unsigned short* __restrict__ P1,
    unsigned short* __restrict__ P2) {
  const int g = blockIdx.x;
  const float* W = (g < 8) ? W1 : W2;
  unsigned short* P = (g < 8) ? P1 : P2;
  const int kc = g & 7, n = threadIdx.x;
  unsigned int packed[16];
#pragma unroll
  for (int i = 0; i < 16; ++i) {
    const float a = W[(((kc << 5) + 2 * i) << 8) + n];
    const float bq = W[(((kc << 5) + 2 * i + 1) << 8) + n];
    packed[i] = bf16rne(a) | (bf16rne(bq) << 16);
  }
  uint4* dst = (uint4*)(P + (((kc << 8) + n) << 5));
#pragma unroll
  for (int q = 0; q < 4; ++q)
    dst[q] = make_uint4(packed[4 * q], packed[4 * q + 1], packed[4 * q + 2], packed[4 * q + 3]);
}

// ---------------- fused up-branch: gather -> bf16 MFMA GEMM1(relu) -> GEMM2 -> transposed out ----------------
#define APITCH 264
#define BPITCH 40
__global__ void __launch_bounds__(256) up_mfma(
    const float* __restrict__ fbuf, const int* __restrict__ idxm,
    const unsigned short* __restrict__ Wu1P, const float* __restrict__ bu1,
    const unsigned short* __restrict__ Wu2P, const float* __restrict__ bu2,
    float* __restrict__ out_feat) {
  __shared__ __align__(16) char smem[64 * APITCH * 2 + 256 * BPITCH * 2 + 2048];
  unsigned short* As = (unsigned short*)smem;                       // 33792 B (later Hs)
  unsigned short* Bs = (unsigned short*)(smem + 64 * APITCH * 2);   // 20480 B (later T)
  float* bias1 = (float*)(smem + 64 * APITCH * 2 + 256 * BPITCH * 2);
  float* bias2 = bias1 + 256;
  float* T = (float*)(smem + 64 * APITCH * 2);                      // 64x66 f32 = 16896 B

  const int t = threadIdx.x;
  const int m0 = blockIdx.x << 6;
  const int quad = (t >> 4) & 3, ln = t & 15, w = t >> 6;

  bias1[t] = bu1[t];
  bias2[t] = bu2[t];

  // gather + cvt: As[r][c] bf16, r = t&63, cols (t>>6)*64..+63
  {
    const int r = t & 63, cseg = t >> 6;
    const int m = m0 + r;
    const long srow = (long)(((m >> 10) << 11) + idxm[m]) << 8;
    const float* src = fbuf + srow + (cseg << 6);
    unsigned short* dst = As + r * APITCH + (cseg << 6);
#pragma unroll
    for (int u = 0; u < 16; ++u) {
      const float4 v = *(const float4*)(src + (u << 2));
      const unsigned int lo = bf16rne(v.x) | (bf16rne(v.y) << 16);
      const unsigned int hi = bf16rne(v.z) | (bf16rne(v.w) << 16);
      *(uint2*)(dst + (u << 2)) = make_uint2(lo, hi);
    }
  }

  f32x4 acc[16];
#pragma unroll
  for (int i = 0; i < 16; ++i) acc[i] = (f32x4){0.f, 0.f, 0.f, 0.f};

  // ---- GEMM1: hu = gathered_f @ Wu1 ----
  for (int kc = 0; kc < 8; ++kc) {
    __syncthreads();
    const uint4* sb = (const uint4*)(Wu1P + (((kc << 8) + t) << 5));
    uint4* db = (uint4*)(Bs + t * BPITCH);
    db[0] = sb[0]; db[1] = sb[1]; db[2] = sb[2]; db[3] = sb[3];
    __syncthreads();
    const short8 a = *(const short8*)(As + ((w << 4) + ln) * APITCH + (kc << 5) + (quad << 3));
#pragma unroll
    for (int nt = 0; nt < 16; ++nt) {
      const short8 b = *(const short8*)(Bs + ((nt << 4) + ln) * BPITCH + (quad << 3));
      acc[nt] = __builtin_amdgcn_mfma_f32_16x16x32_bf16(a, b, acc[nt], 0, 0, 0);
    }
  }

  // ---- relu + bias -> Hs (alias As) ----
  __syncthreads();
  unsigned short* Hs = As;
#pragma unroll
  for (int nt = 0; nt < 16; ++nt) {
    const int c = (nt << 4) + ln;
    const float bb = bias1[c];
#pragma unroll
    for (int rr = 0; rr < 4; ++rr) {
      const float h = fmaxf(acc[nt][rr] + bb, 0.0f);
      Hs[((w << 4) + (quad << 2) + rr) * APITCH + c] = (unsigned short)bf16rne(h);
    }
  }
#pragma unroll
  for (int i = 0; i < 16; ++i) acc[i] = (f32x4){0.f, 0.f, 0.f, 0.f};

  // ---- GEMM2: nf = hu @ Wu2 ----
  for (int kc = 0; kc < 8; ++kc) {
    __syncthreads();
    const uint4* sb = (const uint4*)(Wu2P + (((kc << 8) + t) << 5));
    uint4* db = (uint4*)(Bs + t * BPITCH);
    db[0] = sb[0]; db[1] = sb[1]; db[2] = sb[2]; db[3] = sb[3];
    __syncthreads();
    const short8 a = *(const short8*)(Hs + ((w << 4) + ln) * APITCH + (kc << 5) + (quad << 3));
#pragma unroll
    for (int nt = 0; nt < 16; ++nt) {
      const short8 b = *(const short8*)(Bs + ((nt << 4) + ln) * BPITCH + (quad << 3));
      acc[nt] = __builtin_amdgcn_mfma_f32_16x16x32_bf16(a, b, acc[nt], 0, 0, 0);
    }
  }

  // ---- epilogue: +bu2, transpose via LDS, write out_feat (B,C,K) coalesced ----
  const int bb = m0 >> 10, kbase = m0 & 1023;
  for (int ci = 0; ci < 4; ++ci) {
    __syncthreads();
#pragma unroll
    for (int q = 0; q < 4; ++q) {
      const int nt = (ci << 2) + q;
      const int cloc = (q << 4) + ln;
      const float b2 = bias2[(nt << 4) + ln];
#pragma unroll
      for (int rr = 0; rr < 4; ++rr)
        T[cloc * 66 + ((w << 4) + (quad << 2) + rr)] = acc[nt][rr] + b2;
    }
    __syncthreads();
#pragma unroll
    for (int p = 0; p < 16; ++p) {
      const int cl = (p << 2) + (t >> 6);
      const int m = t & 63;
      out_feat[((long)((bb << 8) + (ci << 6) + cl) << 10) + kbase + m] = T[cl * 66 + m];
    }
  }
}

extern "C" void kernel_launch(void* const* d_in, const int* in_sizes, int n_in,
                              void* d_out, int out_size, void* d_ws, size_t ws_size,
                              hipStream_t stream) {
  const float* xyzs     = (const float*)d_in[0];
  const float* features = (const float*)d_in[1];
  const float* ln_gamma = (const float*)d_in[2];
  const float* ln_beta  = (const float*)d_in[3];
  const float* Wu1      = (const float*)d_in[4];
  const float* bu1      = (const float*)d_in[5];
  const float* Wu2      = (const float*)d_in[6];
  const float* bu2      = (const float*)d_in[7];
  const float* Wd1      = (const float*)d_in[8];
  const float* bd1      = (const float*)d_in[9];
  const float* Wd2      = (const float*)d_in[10];
  const float* bd2      = (const float*)d_in[11];

  char* ws = (char*)d_ws;
  float* fbuf = (float*)ws;                              // 16 MB
  unsigned short* Wu1P = (unsigned short*)(ws + 33554432);  // 128 KB bf16 slabs
  unsigned short* Wu2P = (unsigned short*)(ws + 33685504);  // 128 KB
  float* wv   = (float*)(ws + 50331648);                 // 16384 f32
  int*   idx  = (int*)(ws + 50397184);                   // 8192 i32

  float* out_xyz  = (float*)d_out;            // (8,1024,3)
  float* out_feat = out_xyz + 24576;          // (8,256,1024)
  float* out_idx  = out_feat + 2097152;       // (8,1024)

  prep_w2<<<16, 256, 0, stream>>>(Wu1, Wu2, Wu1P, Wu2P);
  ln_lds<<<256, 256, 0, stream>>>(features, ln_gamma, ln_beta, fbuf);
  wgemm_w<<<256, 512, 0, stream>>>(fbuf, Wd1, bd1, Wd2, bd2, wv);
  topk_kernel<<<8, 1024, 0, stream>>>(wv, xyzs, idx, out_xyz, out_idx);
  up_mfma<<<128, 256, 0, stream>>>(fbuf, idx, Wu1P, bu1, Wu2P, bu2, out_feat);
}